// Round 5
// baseline (46.362 us; speedup 1.0000x reference)
//
#include <hip/hip_runtime.h>
#include <cstdint>

#define NRC 4          // real channels
#define NCC 6          // complex channels
#define HD 64
#define CW 16          // z/out row width (floats)

typedef _Float16 half8 __attribute__((ext_vector_type(8)));
typedef float f32x4 __attribute__((ext_vector_type(4)));

__device__ __forceinline__ uint32_t pkh(float a, float b) {
    auto h = __builtin_amdgcn_cvt_pkrtz(a, b);   // __fp16 ext_vector(2), 4 bytes
    return __builtin_bit_cast(uint32_t, h);
}

// LDS word map (uint32 units), 10240 words = 40960 B -> exactly 4 blocks/CU:
//   [0,    8192)  : h tiles, wave wv at [wv*2048, +2048)  (64 tokens x 32 words, rotated 16B blocks)
//                   layer-1 W^T STAGED TEMPORARILY at [0,2048) (wave0's h area),
//                   read into registers by all waves before wave0 overwrites it.
//   [8192, 10240) : layer-2 W^T f16, persistent (64 rows x 32 words, rotated)
//   route buffer  : reuses own wave's h words [hbase, hbase+128) (dead after final B-reads)
// Each block processes TWO 256-token tiles, amortizing stage+barriers+A1 hoist.
__global__ __launch_bounds__(256, 4) void koop_kernel(
    const float* __restrict__ z,
    const float* __restrict__ W0_r, const float* __restrict__ b0_r,
    const float* __restrict__ Wm_r, const float* __restrict__ bm_r,
    const float* __restrict__ Wl_r, const float* __restrict__ bl_r,
    const float* __restrict__ W0_c, const float* __restrict__ b0_c,
    const float* __restrict__ Wm_c, const float* __restrict__ bm_c,
    const float* __restrict__ Wl_c, const float* __restrict__ bl_c,
    float* __restrict__ out)
{
    __shared__ uint32_t smem[10240];

    const int tid  = threadIdx.x;
    const int lane = tid & 63;
    const int wv   = tid >> 6;
    const int bid  = blockIdx.x;
    const int ch   = bid >> 7;        // 10 ch x 128 groups; consecutive blocks share a channel
    const int grp  = bid & 127;
    const int t0   = grp * 512;

    const bool isReal = (ch < NRC);
    const int  pc     = ch - NRC;
    const int  No     = isReal ? 1 : 2;

    const float* W0 = isReal ? (W0_r + ch * HD) : (W0_c + pc * HD);
    const float* b0 = isReal ? (b0_r + ch * HD) : (b0_c + pc * HD);
    const float* Wl = isReal ? (Wl_r + ch * HD) : (Wl_c + pc * HD * 2);
    const float* bl = isReal ? (bl_r + ch)      : (bl_c + pc * 2);

    const int l15 = lane & 15;
    const int g   = lane >> 4;

    // ---------------- early: z loads for BOTH tiles (overlap weight-stage latency) ----------------
    float xin[2], z1[2], z2[2], sval[2];
    #pragma unroll
    for (int it = 0; it < 2; ++it) {
        const int t = t0 + it * 256 + wv * 64 + lane;
        if (isReal) {
            xin[it] = z[t * CW + ch];
            z1[it] = 0.f; z2[it] = 0.f;
            sval[it] = xin[it];
        } else {
            float2 zz = *(const float2*)(z + t * CW + NRC + 2 * pc);
            xin[it] = 0.f;
            z1[it] = zz.x; z2[it] = zz.y;
            sval[it] = zz.x * zz.x + zz.y * zz.y;
        }
    }

    // ---------------- early: final-layer A fragments (token-independent) ----------------
    half8 Af[2];
    #pragma unroll
    for (int kt = 0; kt < 2; ++kt) {
        half8 a;
        #pragma unroll
        for (int e = 0; e < 8; ++e) {
            const int k = kt * 32 + g * 8 + e;
            float w = (l15 < No) ? Wl[k * No + l15] : 0.f;
            a[e] = (_Float16)w;
        }
        Af[kt] = a;
    }

    // ---------------- stage W^T (f16): L1 -> [0,2048) temp, L2 -> [8192,10240) ----------------
    {
        const int nH = tid & 63;
        const int bb = (tid >> 6) * 2;
        for (int l = 0; l < 2; ++l) {
            const float* Wm = isReal ? (Wm_r + (l * NRC + ch) * HD * HD)
                                     : (Wm_c + (l * NCC + pc) * HD * HD);
            const int base = l ? 8192 : 0;
            #pragma unroll
            for (int r = 0; r < 2; ++r) {
                const int blk = bb + r;                    // k-block (8 k values)
                const float* src = Wm + blk * 8 * HD + nH; // W[k][nH], stride HD per k
                float v0 = src[0],    v1 = src[HD],   v2 = src[2*HD], v3 = src[3*HD];
                float v4 = src[4*HD], v5 = src[5*HD], v6 = src[6*HD], v7 = src[7*HD];
                const int woff = base + nH * 32 + (((blk + nH) & 7) << 2);
                uint4 q = { pkh(v0, v1), pkh(v2, v3), pkh(v4, v5), pkh(v6, v7) };
                *(uint4*)&smem[woff] = q;
            }
        }
    }
    __syncthreads();

    // ---------------- hoist layer-1 A fragments into registers (once per block) ----------------
    half8 A1[4][2];
    #pragma unroll
    for (int m = 0; m < 4; ++m) {
        #pragma unroll
        for (int kt = 0; kt < 2; ++kt) {
            const int row = m * 16 + l15;
            const int blk = kt * 4 + g;
            A1[m][kt] = *(const half8*)&smem[row * 32 + (((blk + row) & 7) << 2)];
        }
    }
    __syncthreads();   // all A1 reads done before wave0 overwrites [0,2048)

    const int hbase = wv * 2048;
    float* smf = (float*)smem;
    const int obase = hbase;          // route words [hbase, hbase+128): 64 tok x 2 f32

    // ================= per-tile loop (wave-local, no more barriers) =================
    #pragma unroll
    for (int it = 0; it < 2; ++it) {
        const int t = t0 + it * 256 + wv * 64 + lane;

        // ---------------- stage 1: h0 = relu(s*W0 + b0), lane = token, uniform W0/b0 ----------------
        #pragma unroll
        for (int blk = 0; blk < 8; ++blk) {
            const int n = blk * 8;
            float a0 = fmaxf(fmaf(sval[it], W0[n+0], b0[n+0]), 0.f);
            float a1 = fmaxf(fmaf(sval[it], W0[n+1], b0[n+1]), 0.f);
            float a2 = fmaxf(fmaf(sval[it], W0[n+2], b0[n+2]), 0.f);
            float a3 = fmaxf(fmaf(sval[it], W0[n+3], b0[n+3]), 0.f);
            float a4 = fmaxf(fmaf(sval[it], W0[n+4], b0[n+4]), 0.f);
            float a5 = fmaxf(fmaf(sval[it], W0[n+5], b0[n+5]), 0.f);
            float a6 = fmaxf(fmaf(sval[it], W0[n+6], b0[n+6]), 0.f);
            float a7 = fmaxf(fmaf(sval[it], W0[n+7], b0[n+7]), 0.f);
            const int woff = hbase + lane * 32 + (((blk + lane) & 7) << 2);
            uint4 q = { pkh(a0, a1), pkh(a2, a3), pkh(a4, a5), pkh(a6, a7) };
            *(uint4*)&smem[woff] = q;
        }

        // ---------------- two hidden layers via MFMA ----------------
        half8 A[4][2];
        #pragma unroll
        for (int m = 0; m < 4; ++m)
            #pragma unroll
            for (int kt = 0; kt < 2; ++kt)
                A[m][kt] = A1[m][kt];

        for (int l = 0; l < 2; ++l) {
            if (l == 1) {
                #pragma unroll
                for (int m = 0; m < 4; ++m) {
                    #pragma unroll
                    for (int kt = 0; kt < 2; ++kt) {
                        const int row = m * 16 + l15;
                        const int blk = kt * 4 + g;
                        A[m][kt] = *(const half8*)&smem[8192 + row * 32 + (((blk + row) & 7) << 2)];
                    }
                }
            }
            const float* bm = isReal ? (bm_r + (l * NRC + ch) * HD)
                                     : (bm_c + (l * NCC + pc) * HD);
            f32x4 bv[4];
            #pragma unroll
            for (int m = 0; m < 4; ++m)
                bv[m] = *(const f32x4*)(bm + m * 16 + g * 4);

            #pragma unroll
            for (int th = 0; th < 2; ++th) {
                f32x4 acc[4][2];
                #pragma unroll
                for (int m = 0; m < 4; ++m)
                    #pragma unroll
                    for (int u = 0; u < 2; ++u)
                        acc[m][u] = bv[m];                // bias folded into C

                #pragma unroll
                for (int u = 0; u < 2; ++u) {
                    const int tt = th * 2 + u;
                    #pragma unroll
                    for (int kt = 0; kt < 2; ++kt) {
                        const int row = tt * 16 + l15;
                        const int blk = kt * 4 + g;
                        half8 Bf = *(const half8*)&smem[hbase + row * 32 + (((blk + row) & 7) << 2)];
                        #pragma unroll
                        for (int m = 0; m < 4; ++m)
                            acc[m][u] = __builtin_amdgcn_mfma_f32_16x16x32_f16(A[m][kt], Bf, acc[m][u], 0, 0, 0);
                    }
                }

                // epilogue: relu + pack f16 + write back (half-disjoint rows; wave-local order)
                #pragma unroll
                for (int u = 0; u < 2; ++u) {
                    const int tt = th * 2 + u;
                    const int row = tt * 16 + l15;
                    #pragma unroll
                    for (int m = 0; m < 4; ++m) {
                        f32x4 v = acc[m][u];
                        float a0 = fmaxf(v[0], 0.f);
                        float a1 = fmaxf(v[1], 0.f);
                        float a2 = fmaxf(v[2], 0.f);
                        float a3 = fmaxf(v[3], 0.f);
                        const int blk  = 2 * m + (g >> 1);
                        const int woff = hbase + row * 32 + (((blk + row) & 7) << 2) + (g & 1) * 2;
                        uint2 q = { pkh(a0, a1), pkh(a2, a3) };
                        *(uint2*)&smem[woff] = q;
                    }
                }
            }
        }

        // ---------------- final layer: out_raw[o][tok] via MFMA (bias in C-init) ----------------
        f32x4 cf0 = (f32x4){0.f, 0.f, 0.f, 0.f};
        if (g == 0) { cf0[0] = bl[0]; if (!isReal) cf0[1] = bl[1]; }
        f32x4 accf[4];
        #pragma unroll
        for (int tt = 0; tt < 4; ++tt) accf[tt] = cf0;
        #pragma unroll
        for (int tt = 0; tt < 4; ++tt) {
            #pragma unroll
            for (int kt = 0; kt < 2; ++kt) {
                const int row = tt * 16 + l15;
                const int blk = kt * 4 + g;
                half8 Bf = *(const half8*)&smem[hbase + row * 32 + (((blk + row) & 7) << 2)];
                accf[tt] = __builtin_amdgcn_mfma_f32_16x16x32_f16(Af[kt], Bf, accf[tt], 0, 0, 0);
            }
        }

        // ---------------- route results to lane = token (wave-local, reuse own h words) ----------------
        if (g == 0) {
            #pragma unroll
            for (int tt = 0; tt < 4; ++tt) {
                const int tok = tt * 16 + l15;
                if (isReal) {
                    smf[obase + tok * 2] = accf[tt][0];
                } else {
                    float2 mo = { accf[tt][0], accf[tt][1] };
                    *(float2*)&smf[obase + tok * 2] = mo;
                }
            }
        }
        __asm__ volatile("s_waitcnt lgkmcnt(0)" ::: "memory");
        __builtin_amdgcn_sched_barrier(0);

        if (isReal) {
            float lam = smf[obase + lane * 2];
            out[t * CW + ch] = xin[it] * lam;
        } else {
            float2 mo = *(const float2*)&smf[obase + lane * 2];
            float ex = __expf(mo.x);
            float mc = ex * __cosf(mo.y);
            float ms = ex * __sinf(mo.y);
            float o1 =  z1[it] * mc + z2[it] * ms;
            float o2 =  z2[it] * mc - z1[it] * ms;
            *(float2*)(out + t * CW + NRC + 2 * pc) = make_float2(o1, o2);
        }
        // ensure route reads of this tile complete before next tile's stage-1 overwrites
        __asm__ volatile("s_waitcnt lgkmcnt(0)" ::: "memory");
        __builtin_amdgcn_sched_barrier(0);
    }
}

extern "C" void kernel_launch(void* const* d_in, const int* in_sizes, int n_in,
                              void* d_out, int out_size, void* d_ws, size_t ws_size,
                              hipStream_t stream) {
    (void)in_sizes; (void)n_in; (void)d_ws; (void)ws_size; (void)out_size;
    const float* z    = (const float*)d_in[0];
    const float* W0_r = (const float*)d_in[1];
    const float* b0_r = (const float*)d_in[2];
    const float* Wm_r = (const float*)d_in[3];
    const float* bm_r = (const float*)d_in[4];
    const float* Wl_r = (const float*)d_in[5];
    const float* bl_r = (const float*)d_in[6];
    const float* W0_c = (const float*)d_in[7];
    const float* b0_c = (const float*)d_in[8];
    const float* Wm_c = (const float*)d_in[9];
    const float* bm_c = (const float*)d_in[10];
    const float* Wl_c = (const float*)d_in[11];
    const float* bl_c = (const float*)d_in[12];
    float* outp = (float*)d_out;

    dim3 grid(1280), block(256);
    koop_kernel<<<grid, block, 0, stream>>>(z, W0_r, b0_r, Wm_r, bm_r, Wl_r, bl_r,
                                            W0_c, b0_c, Wm_c, bm_c, Wl_c, bl_c, outp);
}

// Round 6
// 38.718 us; speedup vs baseline: 1.1974x; 1.1974x over previous
//
#include <hip/hip_runtime.h>
#include <cstdint>

#define NRC 4          // real channels
#define NCC 6          // complex channels
#define HD 64
#define CW 16          // z/out row width (floats)

typedef _Float16 half8  __attribute__((ext_vector_type(8)));
typedef _Float16 half2v __attribute__((ext_vector_type(2)));
typedef float    f32x4  __attribute__((ext_vector_type(4)));

// Block-invariant pre-packed weights (rewritten every call by prep_kernel).
__device__ uint32_t WMPK[40960];   // [ch 10][l 2][frag 512] x half8 (4 u32): hidden-layer A-frags
__device__ uint32_t WLPK[5120];    // [ch 10][frag 128] x half8: final-layer A-frags
__device__ uint32_t W0PKD[320];    // [ch 10][32] packed f16 pairs of W0
__device__ uint32_t B0PKD[320];    // [ch 10][32] packed f16 pairs of b0

__device__ __forceinline__ uint32_t pkh(float a, float b) {
    auto h = __builtin_amdgcn_cvt_pkrtz(a, b);   // __fp16 ext_vector(2), 4 bytes
    return __builtin_bit_cast(uint32_t, h);
}
__device__ __forceinline__ half2v u2h(uint32_t u) { return __builtin_bit_cast(half2v, u); }
__device__ __forceinline__ uint32_t h2u(half2v h) { return __builtin_bit_cast(uint32_t, h); }

__device__ __forceinline__ half2v hmax0(half2v h) {
#if __has_builtin(__builtin_elementwise_max)
    half2v z = {};
    return __builtin_elementwise_max(h, z);      // v_pk_max_f16
#else
    half2v r;
    r[0] = h[0] > (_Float16)0 ? h[0] : (_Float16)0;
    r[1] = h[1] > (_Float16)0 ? h[1] : (_Float16)0;
    return r;
#endif
}
__device__ __forceinline__ half2v hfma(half2v a, half2v b, half2v c) {
#if __has_builtin(__builtin_elementwise_fma)
    return __builtin_elementwise_fma(a, b, c);   // v_pk_fma_f16
#else
    return a * b + c;
#endif
}

// ---------------------------------------------------------------------------
// prep: pack weights into MFMA-fragment order (runs once per call, ~12K threads)
// WMPK frag = ((kt*4+g)*16 + l15)*4 + m ; element e <-> k=(kt*4+g)*8+e, n=m*16+l15
// ---------------------------------------------------------------------------
__global__ void prep_kernel(const float* __restrict__ Wm_r, const float* __restrict__ Wm_c,
                            const float* __restrict__ Wl_r, const float* __restrict__ Wl_c,
                            const float* __restrict__ W0_r, const float* __restrict__ W0_c,
                            const float* __restrict__ b0_r, const float* __restrict__ b0_c)
{
    const int gid = blockIdx.x * 256 + threadIdx.x;
    if (gid < 10240) {                          // hidden-layer fragments
        const int ch = gid >> 10, rem = gid & 1023;
        const int l = rem >> 9, frag = rem & 511;
        const int m = frag & 3, rowsel = frag >> 2;
        const int l15 = rowsel & 15, kg = rowsel >> 4;   // kg = kt*4+g
        const int n = m * 16 + l15;
        const float* W = (ch < NRC) ? (Wm_r + (l * NRC + ch) * HD * HD)
                                    : (Wm_c + (l * NCC + (ch - NRC)) * HD * HD);
        const float* s = W + (kg * 8) * HD + n;          // W[k][n], stride HD per k
        uint4 q = { pkh(s[0],      s[HD]),
                    pkh(s[2*HD],   s[3*HD]),
                    pkh(s[4*HD],   s[5*HD]),
                    pkh(s[6*HD],   s[7*HD]) };
        *(uint4*)&WMPK[gid * 4] = q;
    } else if (gid < 11520) {                   // final-layer fragments
        const int idx = gid - 10240;
        const int ch = idx >> 7, frag = idx & 127;
        const int l15 = frag & 15, kg = frag >> 4;
        const int No = (ch < NRC) ? 1 : 2;
        const float* Wl = (ch < NRC) ? (Wl_r + ch * HD) : (Wl_c + (ch - NRC) * HD * 2);
        float v[8];
        #pragma unroll
        for (int e = 0; e < 8; ++e)
            v[e] = (l15 < No) ? Wl[(kg * 8 + e) * No + l15] : 0.f;
        uint4 q = { pkh(v[0], v[1]), pkh(v[2], v[3]), pkh(v[4], v[5]), pkh(v[6], v[7]) };
        *(uint4*)&WLPK[idx * 4] = q;
    } else if (gid < 12160) {                   // W0 / b0 packed pairs
        const int idx = gid - 11520;
        const int which = idx / 320, r = idx % 320;
        const int ch = r >> 5, j = r & 31;
        const float* src;
        if (which == 0) src = (ch < NRC) ? (W0_r + ch * HD) : (W0_c + (ch - NRC) * HD);
        else            src = (ch < NRC) ? (b0_r + ch * HD) : (b0_c + (ch - NRC) * HD);
        const uint32_t v = pkh(src[2 * j], src[2 * j + 1]);
        if (which == 0) W0PKD[r] = v; else B0PKD[r] = v;
    }
}

// ---------------------------------------------------------------------------
// main: LDS = h tiles only (4 waves x 64 tok x 64 f16, rotated 16B blocks)
//       = 32768 B -> 5 blocks/CU. No __syncthreads anywhere.
// ---------------------------------------------------------------------------
__global__ __launch_bounds__(256, 5) void koop_kernel(
    const float* __restrict__ z,
    const float* __restrict__ bm_r, const float* __restrict__ bl_r,
    const float* __restrict__ bm_c, const float* __restrict__ bl_c,
    float* __restrict__ out)
{
    __shared__ uint32_t smem[8192];

    const int tid  = threadIdx.x;
    const int lane = tid & 63;
    const int wv   = tid >> 6;
    const int bid  = blockIdx.x;
    const int ch   = bid >> 8;        // consecutive blocks share a channel (L2 locality)
    const int tile = bid & 255;
    const int t0   = tile * 256;

    const bool isReal = (ch < NRC);
    const int  pc     = ch - NRC;

    const int l15 = lane & 15;
    const int g   = lane >> 4;

    // ---------------- A-fragments straight from pre-packed global (L2-hit) ----------------
    const uint32_t* wm1 = &WMPK[(ch * 2 + 0) * 2048];
    const uint32_t* wm2 = &WMPK[(ch * 2 + 1) * 2048];
    half8 A1[4][2];
    #pragma unroll
    for (int m = 0; m < 4; ++m)
        #pragma unroll
        for (int kt = 0; kt < 2; ++kt)
            A1[m][kt] = *(const half8*)&wm1[((((kt * 4 + g) * 16 + l15) * 4) + m) * 4];

    half8 Af[2];
    #pragma unroll
    for (int kt = 0; kt < 2; ++kt)
        Af[kt] = *(const half8*)&WLPK[(ch * 128 + (kt * 4 + g) * 16 + l15) * 4];

    // ---------------- per-lane token input ----------------
    const int t = t0 + wv * 64 + lane;
    float xin = 0.f, z1 = 0.f, z2 = 0.f, sval;
    if (isReal) {
        xin = z[t * CW + ch];
        sval = xin;
    } else {
        float2 zz = *(const float2*)(z + t * CW + NRC + 2 * pc);
        z1 = zz.x; z2 = zz.y;
        sval = z1 * z1 + z2 * z2;
    }

    // ---------------- stage 1: h0 = relu(s*W0 + b0), packed f16, lane = token ----------------
    const int hbase = wv * 2048;
    {
        const half2v sv = u2h(pkh(sval, sval));
        const uint32_t* w0p = &W0PKD[ch * 32];
        const uint32_t* b0p = &B0PKD[ch * 32];
        #pragma unroll
        for (int blk = 0; blk < 8; ++blk) {
            uint32_t q[4];
            #pragma unroll
            for (int j = 0; j < 4; ++j) {
                half2v h = hfma(sv, u2h(w0p[blk * 4 + j]), u2h(b0p[blk * 4 + j]));
                q[j] = h2u(hmax0(h));
            }
            const int woff = hbase + lane * 32 + (((blk + lane) & 7) << 2);
            uint4 qq = { q[0], q[1], q[2], q[3] };
            *(uint4*)&smem[woff] = qq;
        }
    }

    // ---------------- two hidden layers via MFMA ----------------
    // D[nH][tok]; D col = token (lane&15), D row = nH = 16*m + 4*g + reg.
    for (int l = 0; l < 2; ++l) {
        half8 A[4][2];
        if (l == 0) {
            #pragma unroll
            for (int m = 0; m < 4; ++m)
                #pragma unroll
                for (int kt = 0; kt < 2; ++kt)
                    A[m][kt] = A1[m][kt];
        } else {
            #pragma unroll
            for (int m = 0; m < 4; ++m)
                #pragma unroll
                for (int kt = 0; kt < 2; ++kt)
                    A[m][kt] = *(const half8*)&wm2[((((kt * 4 + g) * 16 + l15) * 4) + m) * 4];
        }
        const float* bm = isReal ? (bm_r + (l * NRC + ch) * HD)
                                 : (bm_c + (l * NCC + pc) * HD);
        f32x4 bv[4];
        #pragma unroll
        for (int m = 0; m < 4; ++m)
            bv[m] = *(const f32x4*)(bm + m * 16 + g * 4);

        #pragma unroll
        for (int th = 0; th < 2; ++th) {
            f32x4 acc[4][2];
            #pragma unroll
            for (int m = 0; m < 4; ++m)
                #pragma unroll
                for (int u = 0; u < 2; ++u)
                    acc[m][u] = bv[m];                    // bias folded into C

            #pragma unroll
            for (int u = 0; u < 2; ++u) {
                const int tt = th * 2 + u;
                #pragma unroll
                for (int kt = 0; kt < 2; ++kt) {
                    const int row = tt * 16 + l15;
                    const int blk = kt * 4 + g;
                    half8 Bf = *(const half8*)&smem[hbase + row * 32 + (((blk + row) & 7) << 2)];
                    #pragma unroll
                    for (int m = 0; m < 4; ++m)
                        acc[m][u] = __builtin_amdgcn_mfma_f32_16x16x32_f16(A[m][kt], Bf, acc[m][u], 0, 0, 0);
                }
            }

            // epilogue: pack f16 + packed relu + write back (half-disjoint rows)
            #pragma unroll
            for (int u = 0; u < 2; ++u) {
                const int tt = th * 2 + u;
                const int row = tt * 16 + l15;
                #pragma unroll
                for (int m = 0; m < 4; ++m) {
                    f32x4 v = acc[m][u];
                    uint32_t p0 = h2u(hmax0(u2h(pkh(v[0], v[1]))));
                    uint32_t p1 = h2u(hmax0(u2h(pkh(v[2], v[3]))));
                    const int blk  = 2 * m + (g >> 1);
                    const int woff = hbase + row * 32 + (((blk + row) & 7) << 2) + (g & 1) * 2;
                    uint2 q = { p0, p1 };
                    *(uint2*)&smem[woff] = q;
                }
            }
        }
    }

    // ---------------- final layer: out_raw[o][tok] via MFMA (bias in C-init) ----------------
    const float* bl = isReal ? (bl_r + ch) : (bl_c + pc * 2);
    f32x4 cf0 = (f32x4){0.f, 0.f, 0.f, 0.f};
    if (g == 0) { cf0[0] = bl[0]; if (!isReal) cf0[1] = bl[1]; }
    f32x4 accf[4];
    #pragma unroll
    for (int tt = 0; tt < 4; ++tt) accf[tt] = cf0;
    #pragma unroll
    for (int tt = 0; tt < 4; ++tt) {
        #pragma unroll
        for (int kt = 0; kt < 2; ++kt) {
            const int row = tt * 16 + l15;
            const int blk = kt * 4 + g;
            half8 Bf = *(const half8*)&smem[hbase + row * 32 + (((blk + row) & 7) << 2)];
            accf[tt] = __builtin_amdgcn_mfma_f32_16x16x32_f16(Af[kt], Bf, accf[tt], 0, 0, 0);
        }
    }

    // ---------------- route results to lane = token (wave-local, reuse own h words) ----------------
    float* smf = (float*)smem;
    const int obase = hbase;          // words [hbase, hbase+128): 64 tok x 2 f32
    if (g == 0) {
        #pragma unroll
        for (int tt = 0; tt < 4; ++tt) {
            const int tok = tt * 16 + l15;
            if (isReal) {
                smf[obase + tok * 2] = accf[tt][0];
            } else {
                float2 mo = { accf[tt][0], accf[tt][1] };
                *(float2*)&smf[obase + tok * 2] = mo;
            }
        }
    }
    __asm__ volatile("s_waitcnt lgkmcnt(0)" ::: "memory");
    __builtin_amdgcn_sched_barrier(0);

    if (isReal) {
        float lam = smf[obase + lane * 2];
        out[t * CW + ch] = xin * lam;
    } else {
        float2 mo = *(const float2*)&smf[obase + lane * 2];
        float ex = __expf(mo.x);
        float mc = ex * __cosf(mo.y);
        float ms = ex * __sinf(mo.y);
        float o1 =  z1 * mc + z2 * ms;
        float o2 =  z2 * mc - z1 * ms;
        *(float2*)(out + t * CW + NRC + 2 * pc) = make_float2(o1, o2);
    }
}

extern "C" void kernel_launch(void* const* d_in, const int* in_sizes, int n_in,
                              void* d_out, int out_size, void* d_ws, size_t ws_size,
                              hipStream_t stream) {
    (void)in_sizes; (void)n_in; (void)d_ws; (void)ws_size; (void)out_size;
    const float* z    = (const float*)d_in[0];
    const float* W0_r = (const float*)d_in[1];
    const float* b0_r = (const float*)d_in[2];
    const float* Wm_r = (const float*)d_in[3];
    const float* bm_r = (const float*)d_in[4];
    const float* Wl_r = (const float*)d_in[5];
    const float* bl_r = (const float*)d_in[6];
    const float* W0_c = (const float*)d_in[7];
    const float* b0_c = (const float*)d_in[8];
    const float* Wm_c = (const float*)d_in[9];
    const float* bm_c = (const float*)d_in[10];
    const float* Wl_c = (const float*)d_in[11];
    const float* bl_c = (const float*)d_in[12];
    float* outp = (float*)d_out;

    prep_kernel<<<48, 256, 0, stream>>>(Wm_r, Wm_c, Wl_r, Wl_c, W0_r, W0_c, b0_r, b0_c);
    koop_kernel<<<2560, 256, 0, stream>>>(z, bm_r, bl_r, bm_c, bl_c, outp);
}